// Round 20
// baseline (81.763 us; speedup 1.0000x reference)
//
#include <hip/hip_runtime.h>
#include <stdint.h>

#define BN 4
#define CC 256
#define DQ 32
#define HWD 32
#define NN 1024

typedef __attribute__((ext_vector_type(8))) short short8v;
typedef __attribute__((ext_vector_type(16))) float float16v;

// weight-pack element offsets
#define W3OFF0 0
#define W3OFF1 73728
#define W3OFF2 221184
#define W3OFF3 516096
#define WQOFF  1105920
#define WKOFF  1114112
#define WVOFF  1122304
#define WPKTOT 1187840

// prep grid partition
#define PREP_PAD 8880
#define PREP_RPK 4640
#define PREP_XT  512
#define PREP_TOT (PREP_PAD + PREP_RPK + PREP_XT)

// merged conv+projKV grid (512-thr blocks), LPT order: s3,s2,s1,s0 then proj
#define CP_CONV 512
#define CP_PROJ 144
#define CP_TOT  (CP_CONV + CP_PROJ)   // 656 = 8 * 82

#define BUFSTRIDE 10048
#define PROWS 1032   // padded P row stride (shorts)

__device__ __forceinline__ short f2bf(float f) {
  union { float f; uint32_t u; } v; v.f = f;
  uint32_t r = v.u + 0x7FFFu + ((v.u >> 16) & 1u);
  return (short)(r >> 16);
}

__device__ __forceinline__ void gl_lds16(const short* g, short* l) {
  __builtin_amdgcn_global_load_lds(
      (const __attribute__((address_space(1))) void*)g,
      (__attribute__((address_space(3))) void*)l, 16, 0, 0);
}

// ---- fused prep: pad/downsample + weight repack + x transpose --------------
__global__ __launch_bounds__(256) void prep_kernel(
    const float* __restrict__ x0, const float* __restrict__ x1,
    const float* __restrict__ x2, const float* __restrict__ x3,
    const float* __restrict__ w0, const float* __restrict__ w1,
    const float* __restrict__ w2, const float* __restrict__ w3,
    const float* __restrict__ qw, const float* __restrict__ kw,
    const float* __restrict__ vw, const float* __restrict__ x,
    short* __restrict__ pim, short* __restrict__ wpk,
    short* __restrict__ xT2) {
  __shared__ float t[64][33];
  int bid = blockIdx.x;
  int tid = threadIdx.x;
  if (bid < PREP_PAD) {
    int plane = bid / 37;
    int idx = (bid % 37) * 256 + tid;
    if (idx >= 9248) return;
    int b = plane / 60, g = plane % 60;
    int pr = idx / 272;
    int rem = idx % 272;
    int pc = rem >> 3, j = rem & 7;
    const float* xs;
    int s, gb, C;
    if (g < 4)       { xs = x0; s = 16; gb = 0;  C = 32; }
    else if (g < 12) { xs = x1; s = 8;  gb = 4;  C = 64; }
    else if (g < 28) { xs = x2; s = 4;  gb = 12; C = 128; }
    else             { xs = x3; s = 2;  gb = 28; C = 256; }
    float v = 0.f;
    if (pr >= 1 && pr <= 32 && pc >= 1 && pc <= 32) {
      int c = (g - gb) * 8 + j;
      int inHW = 32 * s;
      int ih = (pr - 1) * s + (s >> 1) - 1;
      int iw = (pc - 1) * s + (s >> 1) - 1;
      const float* p = xs + ((size_t)(b * C + c) * inHW + ih) * inHW + iw;
      v = 0.25f * (p[0] + p[1] + p[inHW] + p[inHW + 1]);
    }
    pim[(size_t)plane * 9248 + idx] = f2bf(v);
  } else if (bid < PREP_PAD + PREP_RPK) {
    int idx = (bid - PREP_PAD) * 256 + tid;
    if (idx >= WPKTOT) return;
    const float* w;
    int Cin, chunks, taps, ridx;
    if (idx < W3OFF1)      { w = w0; Cin = 32;  chunks = 2;  taps = 9; ridx = idx; }
    else if (idx < W3OFF2) { w = w1; Cin = 64;  chunks = 4;  taps = 9; ridx = idx - W3OFF1; }
    else if (idx < W3OFF3) { w = w2; Cin = 128; chunks = 8;  taps = 9; ridx = idx - W3OFF2; }
    else if (idx < WQOFF)  { w = w3; Cin = 256; chunks = 16; taps = 9; ridx = idx - W3OFF3; }
    else if (idx < WKOFF)  { w = qw; Cin = 256; chunks = 16; taps = 1; ridx = idx - WQOFF; }
    else if (idx < WVOFF)  { w = kw; Cin = 256; chunks = 16; taps = 1; ridx = idx - WKOFF; }
    else                   { w = vw; Cin = 256; chunks = 16; taps = 1; ridx = idx - WVOFF; }
    int per = taps * 512;
    int g2 = ridx / per;
    int rem = ridx % per;
    int tap = rem >> 9;
    int l = (rem >> 3) & 63;
    int j = rem & 7;
    int ocg = g2 / chunks;
    int chunk = g2 % chunks;
    int oc = ocg * 32 + (l & 31);
    int c = chunk * 16 + ((l >> 5) << 3) + j;
    wpk[idx] = f2bf(w[((size_t)oc * Cin + c) * taps + tap]);
  } else {
    int xb = bid - PREP_PAD - PREP_RPK;
    int nb = xb & 31;
    int cb = (xb >> 5) & 3;
    int b = xb >> 7;
    int n0 = nb * 32, c0 = cb * 64;
    int a = tid >> 5, e = tid & 31;
#pragma unroll
    for (int k = 0; k < 8; ++k)
      t[a + 8 * k][e] = x[((size_t)(b * CC + c0 + a + 8 * k) * NN) + n0 + e];
    __syncthreads();
    int n = tid & 31, cg = tid >> 5;
    short8v o;
#pragma unroll
    for (int jj = 0; jj < 8; ++jj) o[jj] = f2bf(t[cg * 8 + jj][n]);
    *(short8v*)(xT2 + (((size_t)(b * 32) + cb * 8 + cg) * 1024 + n0 + n) * 8) = o;
  }
}

// ---- conv body: 8-wave block (8 output rows), async LDS double-buffer ------
template<int CHUNKS, int GB, int WOFS_>
__device__ __forceinline__ void conv_body_lds(
    const short* __restrict__ pim, const short* __restrict__ wpk,
    const float* __restrict__ sc, const float* __restrict__ bi,
    short* __restrict__ multiT4, short* lds,
    int b, int ocg, int rowq, int sp) {
  int tid = threadIdx.x;
  int w = tid >> 6, l = tid & 63;
  int col = l & 31, chH = l >> 5;
  int r0 = rowq * 8;
  int oc0 = ocg * 32;
  const short* asrc0 = wpk + WOFS_ + (size_t)(ocg * CHUNKS) * 4608;

  auto STAGE = [&](int ck, int buf) {
    short* A = lds + buf * BUFSTRIDE;
    short* B = A + 4608;
    const short* as = asrc0 + (size_t)ck * 4608;
    const short* p0 = pim + ((size_t)(b * 60 + GB + 2 * ck) * 1156 + r0 * 34) * 8;
    const short* p1 = pim + ((size_t)(b * 60 + GB + 2 * ck + 1) * 1156 + r0 * 34) * 8;
    gl_lds16(as + tid * 8, A + (size_t)w * 512);
    if (tid < 64) gl_lds16(as + (512 + tid) * 8, A + 4096);
    const short* src = (tid < 340) ? (p0 + tid * 8) : (p1 + (tid - 340) * 8);
    gl_lds16(src, B + (size_t)w * 512);
    if (tid < 168)
      gl_lds16(p1 + (172 + tid) * 8, B + 4096 + (size_t)w * 512);
  };

  float16v acc;
#pragma unroll
  for (int r = 0; r < 16; ++r) acc[r] = 0.f;

  STAGE(0, 0);
  __syncthreads();
  int cur = 0;
#pragma unroll
  for (int ck = 0; ck < CHUNKS; ++ck) {
    if (ck + 1 < CHUNKS) STAGE(ck + 1, cur ^ 1);
    const short* A = lds + cur * BUFSTRIDE;
    const short* B = A + 4608;
#pragma unroll
    for (int ky = 0; ky < 3; ++ky)
#pragma unroll
      for (int kx = 0; kx < 3; ++kx) {
        short8v av = *(const short8v*)&A[(ky * 3 + kx) * 512 + l * 8];
        short8v bv = *(const short8v*)&B[chH * 2720 + (w + ky) * 272 + (col + kx) * 8];
        acc = __builtin_amdgcn_mfma_f32_32x32x16_bf16(av, bv, acc, 0, 0, 0);
      }
    __syncthreads();
    cur ^= 1;
  }

  float* sTw = ((float*)lds) + w * (32 * 33);
#pragma unroll
  for (int r = 0; r < 16; ++r) {
    int ocl = (r & 3) + ((r >> 2) << 3) + (chH << 2);
    float t = fmaf(acc[r], sc[oc0 + ocl], bi[oc0 + ocl]);
    sTw[ocl * 33 + col] = t > 0.f ? t : 0.f;
  }
  __syncthreads();
#pragma unroll
  for (int it = 0; it < 2; ++it) {
    int idx = l + (it << 6);
    int cg = idx >> 5;
    int c2 = idx & 31;
    short8v o;
#pragma unroll
    for (int jj = 0; jj < 8; ++jj) o[jj] = f2bf(sTw[(cg * 8 + jj) * 33 + c2]);
    *(short8v*)(multiT4 + (size_t)sp * 1048576 +
                (((size_t)(b * 32) + ocg * 4 + cg) * 1024 + (r0 + w) * 32 + c2) * 8) = o;
  }
}

// ---- merged conv (8-wave LDS staged) + K/V projections, LPT + XCD swizzle --
__global__ __launch_bounds__(512) void convproj2_kernel(
    const short* __restrict__ pim, const short* __restrict__ wpk,
    const short* __restrict__ xT2,
    const float* __restrict__ sc0, const float* __restrict__ bi0,
    const float* __restrict__ sc1, const float* __restrict__ bi1,
    const float* __restrict__ sc2, const float* __restrict__ bi2,
    const float* __restrict__ sc3, const float* __restrict__ bi3,
    const float* __restrict__ kbi, const float* __restrict__ vbi,
    const float* __restrict__ relh, const float* __restrict__ relw,
    short* __restrict__ multiT4, float* __restrict__ kpbuf,
    short* __restrict__ vbf2) {
  __shared__ short lds[2 * BUFSTRIDE];
  // XCD-aware bijective swizzle: 656 = 8 x 82; launch-bid lands on XCD bid%8,
  // works w = [82*xcd, 82*(xcd+1)) are consecutive -> A-panel quads share L2.
  int bid = (blockIdx.x % 8) * 82 + blockIdx.x / 8;
  int tid = threadIdx.x;
  if (bid < CP_CONV) {
    int s = 3 - (bid >> 7);
    int cb = bid & 127;
    int rowq = cb & 3;
    int ocg = (cb >> 2) & 7;
    int b = cb >> 5;
    if (s == 3)      conv_body_lds<16, 28, W3OFF3>(pim, wpk, sc3, bi3, multiT4, lds, b, ocg, rowq, 3);
    else if (s == 2) conv_body_lds<8, 12, W3OFF2>(pim, wpk, sc2, bi2, multiT4, lds, b, ocg, rowq, 2);
    else if (s == 1) conv_body_lds<4, 4, W3OFF1>(pim, wpk, sc1, bi1, multiT4, lds, b, ocg, rowq, 1);
    else             conv_body_lds<2, 0, W3OFF0>(pim, wpk, sc0, bi0, multiT4, lds, b, ocg, rowq, 0);
  } else {
    int u = (bid - CP_CONV) * 8 + (tid >> 6);
    int l = tid & 63;
    int mode, b, nt, ocg;
    const short* ap;
    const float* bias;
    if (u < 128) { mode = 1; b = u >> 5; nt = u & 31; ocg = 0; ap = wpk + WKOFF; bias = kbi; }
    else { int t2 = u - 128; mode = 2; nt = t2 & 31; ocg = (t2 >> 5) & 7; b = t2 >> 8; ap = wpk + WVOFF + (size_t)ocg * 16 * 512; bias = vbi; }
    int n = nt * 32 + (l & 31);
    int half = l >> 5;
    ap += l * 8;
    float16v acc;
#pragma unroll
    for (int r = 0; r < 16; ++r) acc[r] = 0.f;
#pragma unroll
    for (int ck = 0; ck < 16; ++ck) {
      short8v av = *(const short8v*)(ap + ck * 512);
      short8v bv = *(const short8v*)(xT2 + (((size_t)(b * 32) + ck * 2 + half) * 1024 + n) * 8);
      acc = __builtin_amdgcn_mfma_f32_32x32x16_bf16(av, bv, acc, 0, 0, 0);
    }
#pragma unroll
    for (int r = 0; r < 16; ++r) {
      int oc = ocg * 32 + (r & 3) + ((r >> 2) << 3) + (half << 2);
      float t = acc[r] + bias[oc];
      if (mode == 1) {
        t += relh[oc * 32 + (n >> 5)] + relw[oc * 32 + (n & 31)];
        kpbuf[((size_t)b * DQ + oc) * NN + n] = t;
      } else {
        vbf2[(((size_t)(b * 128) + (n >> 3)) * 256 + oc) * 8 + (n & 7)] = f2bf(t);
      }
    }
  }
}

// ---- attn (16 rows/block, 512 thr) with fused q-proj AND out GEMM ----------
// XCD swizzle: 256 = 8 x 32 -> each XCD handles 32 consecutive work-items
// (one half-batch): V_b/kp_b/multiT4_b stay L2-resident per XCD.
__global__ __launch_bounds__(512) void attnout2_kernel(
    const short* __restrict__ multiT4, const short* __restrict__ wpk,
    const float* __restrict__ qbi, const float* __restrict__ kp,
    const short* __restrict__ vbf2, const float* __restrict__ x,
    const float* __restrict__ gamma, float* __restrict__ attn,
    float* __restrict__ out) {
  __shared__ union {
    float lds_q[4][32][33];
    short P[16][PROWS];
  } u;
  __shared__ float qs[DQ][16];
  __shared__ float redm[8][16], reds[8][16];
  int bidx = (blockIdx.x % 8) * 32 + blockIdx.x / 8;
  int ig = bidx & 63;
  int b = bidx >> 6;
  int i0 = ig * 16;
  int tid = threadIdx.x;
  int w = tid >> 6, l = tid & 63;
  int it0 = (ig >> 1) * 32;

  if (w < 4) {
    int n = it0 + (l & 31);
    int half = l >> 5;
    const short* ap = wpk + WQOFF + l * 8;
    float16v acc;
#pragma unroll
    for (int r = 0; r < 16; ++r) acc[r] = 0.f;
#pragma unroll
    for (int c4 = 0; c4 < 4; ++c4) {
      int ck = w * 4 + c4;
      short8v av = *(const short8v*)(ap + ck * 512);
      size_t bix = (((size_t)(b * 32) + ck * 2 + half) * 1024 + n) * 8;
      short8v bv0 = *(const short8v*)(multiT4 + bix);
      short8v bv1 = *(const short8v*)(multiT4 + 1048576 + bix);
      short8v bv2 = *(const short8v*)(multiT4 + 2097152 + bix);
      short8v bv3 = *(const short8v*)(multiT4 + 3145728 + bix);
      acc = __builtin_amdgcn_mfma_f32_32x32x16_bf16(av, bv0, acc, 0, 0, 0);
      acc = __builtin_amdgcn_mfma_f32_32x32x16_bf16(av, bv1, acc, 0, 0, 0);
      acc = __builtin_amdgcn_mfma_f32_32x32x16_bf16(av, bv2, acc, 0, 0, 0);
      acc = __builtin_amdgcn_mfma_f32_32x32x16_bf16(av, bv3, acc, 0, 0, 0);
    }
#pragma unroll
    for (int r = 0; r < 16; ++r) {
      int oc = (r & 3) + ((r >> 2) << 3) + (half << 2);
      u.lds_q[w][oc][l & 31] = acc[r];
    }
  }
  __syncthreads();
  {
    int c = tid >> 4, rr = tid & 15;
    int nl = (ig & 1) * 16 + rr;
    qs[c][rr] = u.lds_q[0][c][nl] + u.lds_q[1][c][nl] + u.lds_q[2][c][nl] +
                u.lds_q[3][c][nl] + qbi[c];
  }
  __syncthreads();

  float e[16][2];
#pragma unroll
  for (int r = 0; r < 16; ++r) { e[r][0] = 0.f; e[r][1] = 0.f; }
  const float* kpb = kp + (size_t)b * DQ * NN + tid;
  for (int c = 0; c < DQ; ++c) {
    float k0 = kpb[0], k1 = kpb[512];
    kpb += NN;
#pragma unroll
    for (int r = 0; r < 16; ++r) {
      float qv = qs[c][r];
      e[r][0] = fmaf(qv, k0, e[r][0]);
      e[r][1] = fmaf(qv, k1, e[r][1]);
    }
  }
#pragma unroll
  for (int r = 0; r < 16; ++r) {
    float mm = fmaxf(e[r][0], e[r][1]);
#pragma unroll
    for (int off = 32; off > 0; off >>= 1) mm = fmaxf(mm, __shfl_xor(mm, off));
    if (l == 0) redm[w][r] = mm;
  }
  __syncthreads();
#pragma unroll
  for (int r = 0; r < 16; ++r) {
    float mm = redm[0][r];
#pragma unroll
    for (int q = 1; q < 8; ++q) mm = fmaxf(mm, redm[q][r]);
    e[r][0] = __expf(e[r][0] - mm);
    e[r][1] = __expf(e[r][1] - mm);
    float ss = e[r][0] + e[r][1];
#pragma unroll
    for (int off = 32; off > 0; off >>= 1) ss += __shfl_xor(ss, off);
    if (l == 0) reds[w][r] = ss;
  }
  __syncthreads();
#pragma unroll
  for (int r = 0; r < 16; ++r) {
    float ss = reds[0][r];
#pragma unroll
    for (int q = 1; q < 8; ++q) ss += reds[q][r];
    float inv = 1.f / ss;
    int i = i0 + r;
    size_t base = ((size_t)b * NN + i) * NN + tid;
    float a0 = e[r][0] * inv, a1 = e[r][1] * inv;
    attn[base] = a0;
    attn[base + 512] = a1;
    u.P[r][tid] = f2bf(a0);
    u.P[r][tid + 512] = f2bf(a1);
  }
  __syncthreads();

  {
    int half = l >> 5, lane31 = l & 31;
    float g = gamma[0];
    int c0 = w * 32;
    const short* vbase = vbf2 + (((size_t)(b * 128) + half) * 256 + c0 + lane31) * 8;
    const short* prow = &u.P[lane31 & 15][half * 8];
    float16v acc;
#pragma unroll
    for (int r = 0; r < 16; ++r) acc[r] = 0.f;
#pragma unroll 4
    for (int jc = 0; jc < 64; ++jc) {
      short8v av = *(const short8v*)(vbase + (size_t)jc * 2 * 256 * 8);
      short8v bv = *(const short8v*)(prow + jc * 16);
      acc = __builtin_amdgcn_mfma_f32_32x32x16_bf16(av, bv, acc, 0, 0, 0);
    }
    if (lane31 < 16) {
      int i = i0 + lane31;
#pragma unroll
      for (int r = 0; r < 16; ++r) {
        int c = c0 + (r & 3) + ((r >> 2) << 3) + (half << 2);
        size_t off = ((size_t)b * CC + c) * NN + i;
        out[off] = fmaf(g, acc[r], x[off]);
      }
    }
  }
}

extern "C" void kernel_launch(void* const* d_in, const int* in_sizes, int n_in,
                              void* d_out, int out_size, void* d_ws, size_t ws_size,
                              hipStream_t stream) {
  const float* x    = (const float*)d_in[0];
  const float* x0   = (const float*)d_in[1];
  const float* x1   = (const float*)d_in[2];
  const float* x2   = (const float*)d_in[3];
  const float* x3   = (const float*)d_in[4];
  const float* w0   = (const float*)d_in[5];
  const float* s0   = (const float*)d_in[6];
  const float* b0   = (const float*)d_in[7];
  const float* w1   = (const float*)d_in[8];
  const float* s1   = (const float*)d_in[9];
  const float* b1   = (const float*)d_in[10];
  const float* w2   = (const float*)d_in[11];
  const float* s2   = (const float*)d_in[12];
  const float* b2   = (const float*)d_in[13];
  const float* w3   = (const float*)d_in[14];
  const float* s3   = (const float*)d_in[15];
  const float* b3   = (const float*)d_in[16];
  const float* qw   = (const float*)d_in[17];
  const float* qbi  = (const float*)d_in[18];
  const float* kw   = (const float*)d_in[19];
  const float* kbi  = (const float*)d_in[20];
  const float* vw   = (const float*)d_in[21];
  const float* vbi  = (const float*)d_in[22];
  const float* relh = (const float*)d_in[23];
  const float* relw = (const float*)d_in[24];
  const float* gamma= (const float*)d_in[25];

  float* ws = (float*)d_ws;
  short* pim     = (short*)ws;                 // 2,219,520 sh
  short* multiT4 = (short*)(ws + 1109760);     // 4,194,304 sh
  float* kpbuf   = ws + 3337984;               // 131,072 f
  short* xT2     = (short*)(ws + 3469056);     // 1,048,576 sh
  short* vbf2    = (short*)(ws + 3993344);     // 1,048,576 sh
  short* wpk     = (short*)(ws + 4517632);     // 1,187,840 sh

  float* out  = (float*)d_out;
  float* attn = out + (size_t)BN * CC * NN;

  prep_kernel<<<PREP_TOT, 256, 0, stream>>>(x0, x1, x2, x3, w0, w1, w2, w3,
                                            qw, kw, vw, x, pim, wpk, xT2);

  convproj2_kernel<<<CP_TOT, 512, 0, stream>>>(pim, wpk, xT2,
                                               s0, b0, s1, b1, s2, b2, s3, b3,
                                               kbi, vbi, relh, relw,
                                               multiT4, kpbuf, vbf2);

  attnout2_kernel<<<256, 512, 0, stream>>>(multiT4, wpk, qbi, kpbuf,
                                           vbf2, x, gamma, attn, out);
}

// Round 21
// 74.442 us; speedup vs baseline: 1.0984x; 1.0984x over previous
//
#include <hip/hip_runtime.h>
#include <stdint.h>

#define BN 4
#define CC 256
#define DQ 32
#define HWD 32
#define NN 1024

typedef __attribute__((ext_vector_type(8))) short short8v;
typedef __attribute__((ext_vector_type(16))) float float16v;

// weight-pack element offsets
#define W3OFF0 0
#define W3OFF1 73728
#define W3OFF2 221184
#define W3OFF3 516096
#define WQOFF  1105920
#define WKOFF  1114112
#define WVOFF  1122304
#define WPKTOT 1187840

// prep grid partition
#define PREP_PAD 8880
#define PREP_RPK 4640
#define PREP_XT  512
#define PREP_TOT (PREP_PAD + PREP_RPK + PREP_XT)

// merged conv+projKV grid (512-thr blocks), LPT order: s3,s2,s1,s0 then proj
#define CP_CONV 512
#define CP_PROJ 144
#define CP_TOT  (CP_CONV + CP_PROJ)

#define BUFSTRIDE 10048
#define PROWS 1032   // padded P row stride (shorts)

__device__ __forceinline__ short f2bf(float f) {
  union { float f; uint32_t u; } v; v.f = f;
  uint32_t r = v.u + 0x7FFFu + ((v.u >> 16) & 1u);
  return (short)(r >> 16);
}

__device__ __forceinline__ void gl_lds16(const short* g, short* l) {
  __builtin_amdgcn_global_load_lds(
      (const __attribute__((address_space(1))) void*)g,
      (__attribute__((address_space(3))) void*)l, 16, 0, 0);
}

// ---- fused prep: pad/downsample + weight repack + x transpose --------------
__global__ __launch_bounds__(256) void prep_kernel(
    const float* __restrict__ x0, const float* __restrict__ x1,
    const float* __restrict__ x2, const float* __restrict__ x3,
    const float* __restrict__ w0, const float* __restrict__ w1,
    const float* __restrict__ w2, const float* __restrict__ w3,
    const float* __restrict__ qw, const float* __restrict__ kw,
    const float* __restrict__ vw, const float* __restrict__ x,
    short* __restrict__ pim, short* __restrict__ wpk,
    short* __restrict__ xT2) {
  __shared__ float t[64][33];
  int bid = blockIdx.x;
  int tid = threadIdx.x;
  if (bid < PREP_PAD) {
    int plane = bid / 37;
    int idx = (bid % 37) * 256 + tid;
    if (idx >= 9248) return;
    int b = plane / 60, g = plane % 60;
    int pr = idx / 272;
    int rem = idx % 272;
    int pc = rem >> 3, j = rem & 7;
    const float* xs;
    int s, gb, C;
    if (g < 4)       { xs = x0; s = 16; gb = 0;  C = 32; }
    else if (g < 12) { xs = x1; s = 8;  gb = 4;  C = 64; }
    else if (g < 28) { xs = x2; s = 4;  gb = 12; C = 128; }
    else             { xs = x3; s = 2;  gb = 28; C = 256; }
    float v = 0.f;
    if (pr >= 1 && pr <= 32 && pc >= 1 && pc <= 32) {
      int c = (g - gb) * 8 + j;
      int inHW = 32 * s;
      int ih = (pr - 1) * s + (s >> 1) - 1;
      int iw = (pc - 1) * s + (s >> 1) - 1;
      const float* p = xs + ((size_t)(b * C + c) * inHW + ih) * inHW + iw;
      v = 0.25f * (p[0] + p[1] + p[inHW] + p[inHW + 1]);
    }
    pim[(size_t)plane * 9248 + idx] = f2bf(v);
  } else if (bid < PREP_PAD + PREP_RPK) {
    int idx = (bid - PREP_PAD) * 256 + tid;
    if (idx >= WPKTOT) return;
    const float* w;
    int Cin, chunks, taps, ridx;
    if (idx < W3OFF1)      { w = w0; Cin = 32;  chunks = 2;  taps = 9; ridx = idx; }
    else if (idx < W3OFF2) { w = w1; Cin = 64;  chunks = 4;  taps = 9; ridx = idx - W3OFF1; }
    else if (idx < W3OFF3) { w = w2; Cin = 128; chunks = 8;  taps = 9; ridx = idx - W3OFF2; }
    else if (idx < WQOFF)  { w = w3; Cin = 256; chunks = 16; taps = 9; ridx = idx - W3OFF3; }
    else if (idx < WKOFF)  { w = qw; Cin = 256; chunks = 16; taps = 1; ridx = idx - WQOFF; }
    else if (idx < WVOFF)  { w = kw; Cin = 256; chunks = 16; taps = 1; ridx = idx - WKOFF; }
    else                   { w = vw; Cin = 256; chunks = 16; taps = 1; ridx = idx - WVOFF; }
    int per = taps * 512;
    int g2 = ridx / per;
    int rem = ridx % per;
    int tap = rem >> 9;
    int l = (rem >> 3) & 63;
    int j = rem & 7;
    int ocg = g2 / chunks;
    int chunk = g2 % chunks;
    int oc = ocg * 32 + (l & 31);
    int c = chunk * 16 + ((l >> 5) << 3) + j;
    wpk[idx] = f2bf(w[((size_t)oc * Cin + c) * taps + tap]);
  } else {
    int xb = bid - PREP_PAD - PREP_RPK;
    int nb = xb & 31;
    int cb = (xb >> 5) & 3;
    int b = xb >> 7;
    int n0 = nb * 32, c0 = cb * 64;
    int a = tid >> 5, e = tid & 31;
#pragma unroll
    for (int k = 0; k < 8; ++k)
      t[a + 8 * k][e] = x[((size_t)(b * CC + c0 + a + 8 * k) * NN) + n0 + e];
    __syncthreads();
    int n = tid & 31, cg = tid >> 5;
    short8v o;
#pragma unroll
    for (int jj = 0; jj < 8; ++jj) o[jj] = f2bf(t[cg * 8 + jj][n]);
    *(short8v*)(xT2 + (((size_t)(b * 32) + cb * 8 + cg) * 1024 + n0 + n) * 8) = o;
  }
}

// ---- conv body: 8-wave block (8 output rows), async LDS double-buffer ------
template<int CHUNKS, int GB, int WOFS_>
__device__ __forceinline__ void conv_body_lds(
    const short* __restrict__ pim, const short* __restrict__ wpk,
    const float* __restrict__ sc, const float* __restrict__ bi,
    short* __restrict__ multiT4, short* lds,
    int b, int ocg, int rowq, int sp) {
  int tid = threadIdx.x;
  int w = tid >> 6, l = tid & 63;
  int col = l & 31, chH = l >> 5;
  int r0 = rowq * 8;
  int oc0 = ocg * 32;
  const short* asrc0 = wpk + WOFS_ + (size_t)(ocg * CHUNKS) * 4608;

  auto STAGE = [&](int ck, int buf) {
    short* A = lds + buf * BUFSTRIDE;
    short* B = A + 4608;
    const short* as = asrc0 + (size_t)ck * 4608;
    const short* p0 = pim + ((size_t)(b * 60 + GB + 2 * ck) * 1156 + r0 * 34) * 8;
    const short* p1 = pim + ((size_t)(b * 60 + GB + 2 * ck + 1) * 1156 + r0 * 34) * 8;
    gl_lds16(as + tid * 8, A + (size_t)w * 512);
    if (tid < 64) gl_lds16(as + (512 + tid) * 8, A + 4096);
    const short* src = (tid < 340) ? (p0 + tid * 8) : (p1 + (tid - 340) * 8);
    gl_lds16(src, B + (size_t)w * 512);
    if (tid < 168)
      gl_lds16(p1 + (172 + tid) * 8, B + 4096 + (size_t)w * 512);
  };

  float16v acc;
#pragma unroll
  for (int r = 0; r < 16; ++r) acc[r] = 0.f;

  STAGE(0, 0);
  __syncthreads();
  int cur = 0;
#pragma unroll
  for (int ck = 0; ck < CHUNKS; ++ck) {
    if (ck + 1 < CHUNKS) STAGE(ck + 1, cur ^ 1);
    const short* A = lds + cur * BUFSTRIDE;
    const short* B = A + 4608;
#pragma unroll
    for (int ky = 0; ky < 3; ++ky)
#pragma unroll
      for (int kx = 0; kx < 3; ++kx) {
        short8v av = *(const short8v*)&A[(ky * 3 + kx) * 512 + l * 8];
        short8v bv = *(const short8v*)&B[chH * 2720 + (w + ky) * 272 + (col + kx) * 8];
        acc = __builtin_amdgcn_mfma_f32_32x32x16_bf16(av, bv, acc, 0, 0, 0);
      }
    __syncthreads();
    cur ^= 1;
  }

  float* sTw = ((float*)lds) + w * (32 * 33);
#pragma unroll
  for (int r = 0; r < 16; ++r) {
    int ocl = (r & 3) + ((r >> 2) << 3) + (chH << 2);
    float t = fmaf(acc[r], sc[oc0 + ocl], bi[oc0 + ocl]);
    sTw[ocl * 33 + col] = t > 0.f ? t : 0.f;
  }
  __syncthreads();
#pragma unroll
  for (int it = 0; it < 2; ++it) {
    int idx = l + (it << 6);
    int cg = idx >> 5;
    int c2 = idx & 31;
    short8v o;
#pragma unroll
    for (int jj = 0; jj < 8; ++jj) o[jj] = f2bf(sTw[(cg * 8 + jj) * 33 + c2]);
    *(short8v*)(multiT4 + (size_t)sp * 1048576 +
                (((size_t)(b * 32) + ocg * 4 + cg) * 1024 + (r0 + w) * 32 + c2) * 8) = o;
  }
}

// ---- merged conv (8-wave LDS staged) + K/V projections, LPT-ordered --------
__global__ __launch_bounds__(512) void convproj2_kernel(
    const short* __restrict__ pim, const short* __restrict__ wpk,
    const short* __restrict__ xT2,
    const float* __restrict__ sc0, const float* __restrict__ bi0,
    const float* __restrict__ sc1, const float* __restrict__ bi1,
    const float* __restrict__ sc2, const float* __restrict__ bi2,
    const float* __restrict__ sc3, const float* __restrict__ bi3,
    const float* __restrict__ kbi, const float* __restrict__ vbi,
    const float* __restrict__ relh, const float* __restrict__ relw,
    short* __restrict__ multiT4, float* __restrict__ kpbuf,
    short* __restrict__ vbf2) {
  __shared__ short lds[2 * BUFSTRIDE];
  int bid = blockIdx.x;
  int tid = threadIdx.x;
  if (bid < CP_CONV) {
    int s = 3 - (bid >> 7);
    int cb = bid & 127;
    int rowq = cb & 3;
    int ocg = (cb >> 2) & 7;
    int b = cb >> 5;
    if (s == 3)      conv_body_lds<16, 28, W3OFF3>(pim, wpk, sc3, bi3, multiT4, lds, b, ocg, rowq, 3);
    else if (s == 2) conv_body_lds<8, 12, W3OFF2>(pim, wpk, sc2, bi2, multiT4, lds, b, ocg, rowq, 2);
    else if (s == 1) conv_body_lds<4, 4, W3OFF1>(pim, wpk, sc1, bi1, multiT4, lds, b, ocg, rowq, 1);
    else             conv_body_lds<2, 0, W3OFF0>(pim, wpk, sc0, bi0, multiT4, lds, b, ocg, rowq, 0);
  } else {
    int u = (bid - CP_CONV) * 8 + (tid >> 6);
    int l = tid & 63;
    int mode, b, nt, ocg;
    const short* ap;
    const float* bias;
    if (u < 128) { mode = 1; b = u >> 5; nt = u & 31; ocg = 0; ap = wpk + WKOFF; bias = kbi; }
    else { int t2 = u - 128; mode = 2; nt = t2 & 31; ocg = (t2 >> 5) & 7; b = t2 >> 8; ap = wpk + WVOFF + (size_t)ocg * 16 * 512; bias = vbi; }
    int n = nt * 32 + (l & 31);
    int half = l >> 5;
    ap += l * 8;
    float16v acc;
#pragma unroll
    for (int r = 0; r < 16; ++r) acc[r] = 0.f;
#pragma unroll
    for (int ck = 0; ck < 16; ++ck) {
      short8v av = *(const short8v*)(ap + ck * 512);
      short8v bv = *(const short8v*)(xT2 + (((size_t)(b * 32) + ck * 2 + half) * 1024 + n) * 8);
      acc = __builtin_amdgcn_mfma_f32_32x32x16_bf16(av, bv, acc, 0, 0, 0);
    }
#pragma unroll
    for (int r = 0; r < 16; ++r) {
      int oc = ocg * 32 + (r & 3) + ((r >> 2) << 3) + (half << 2);
      float t = acc[r] + bias[oc];
      if (mode == 1) {
        t += relh[oc * 32 + (n >> 5)] + relw[oc * 32 + (n & 31)];
        kpbuf[((size_t)b * DQ + oc) * NN + n] = t;
      } else {
        vbf2[(((size_t)(b * 128) + (n >> 3)) * 256 + oc) * 8 + (n & 7)] = f2bf(t);
      }
    }
  }
}

// ---- attn (16 rows/block, 512 thr) with fused q-proj AND out GEMM ----------
__global__ __launch_bounds__(512) void attnout2_kernel(
    const short* __restrict__ multiT4, const short* __restrict__ wpk,
    const float* __restrict__ qbi, const float* __restrict__ kp,
    const short* __restrict__ vbf2, const float* __restrict__ x,
    const float* __restrict__ gamma, float* __restrict__ attn,
    float* __restrict__ out) {
  __shared__ union {
    float lds_q[4][32][33];   // 16.9 KB (q-proj partials, waves 0-3)
    short P[16][PROWS];       // 33 KB (bf16 P rows)
  } u;
  __shared__ float qs[DQ][16];
  __shared__ float redm[8][16], reds[8][16];
  int bidx = blockIdx.x;
  int ig = bidx & 63;
  int b = bidx >> 6;
  int i0 = ig * 16;
  int tid = threadIdx.x;
  int w = tid >> 6, l = tid & 63;
  int it0 = (ig >> 1) * 32;

  // ---- q tile (waves 0-3, chunks w*4..w*4+3, 4 scale partials) ------------
  if (w < 4) {
    int n = it0 + (l & 31);
    int half = l >> 5;
    const short* ap = wpk + WQOFF + l * 8;
    float16v acc;
#pragma unroll
    for (int r = 0; r < 16; ++r) acc[r] = 0.f;
#pragma unroll
    for (int c4 = 0; c4 < 4; ++c4) {
      int ck = w * 4 + c4;
      short8v av = *(const short8v*)(ap + ck * 512);
      size_t bix = (((size_t)(b * 32) + ck * 2 + half) * 1024 + n) * 8;
      short8v bv0 = *(const short8v*)(multiT4 + bix);
      short8v bv1 = *(const short8v*)(multiT4 + 1048576 + bix);
      short8v bv2 = *(const short8v*)(multiT4 + 2097152 + bix);
      short8v bv3 = *(const short8v*)(multiT4 + 3145728 + bix);
      acc = __builtin_amdgcn_mfma_f32_32x32x16_bf16(av, bv0, acc, 0, 0, 0);
      acc = __builtin_amdgcn_mfma_f32_32x32x16_bf16(av, bv1, acc, 0, 0, 0);
      acc = __builtin_amdgcn_mfma_f32_32x32x16_bf16(av, bv2, acc, 0, 0, 0);
      acc = __builtin_amdgcn_mfma_f32_32x32x16_bf16(av, bv3, acc, 0, 0, 0);
    }
#pragma unroll
    for (int r = 0; r < 16; ++r) {
      int oc = (r & 3) + ((r >> 2) << 3) + (half << 2);
      u.lds_q[w][oc][l & 31] = acc[r];
    }
  }
  __syncthreads();
  {
    int c = tid >> 4, rr = tid & 15;     // 32 x 16 = 512 threads exactly
    int nl = (ig & 1) * 16 + rr;
    qs[c][rr] = u.lds_q[0][c][nl] + u.lds_q[1][c][nl] + u.lds_q[2][c][nl] +
                u.lds_q[3][c][nl] + qbi[c];
  }
  __syncthreads();

  // ---- energy (thread: j = tid, tid+512) + softmax ------------------------
  float e[16][2];
#pragma unroll
  for (int r = 0; r < 16; ++r) { e[r][0] = 0.f; e[r][1] = 0.f; }
  const float* kpb = kp + (size_t)b * DQ * NN + tid;
  for (int c = 0; c < DQ; ++c) {
    float k0 = kpb[0], k1 = kpb[512];
    kpb += NN;
#pragma unroll
    for (int r = 0; r < 16; ++r) {
      float qv = qs[c][r];
      e[r][0] = fmaf(qv, k0, e[r][0]);
      e[r][1] = fmaf(qv, k1, e[r][1]);
    }
  }
#pragma unroll
  for (int r = 0; r < 16; ++r) {
    float mm = fmaxf(e[r][0], e[r][1]);
#pragma unroll
    for (int off = 32; off > 0; off >>= 1) mm = fmaxf(mm, __shfl_xor(mm, off));
    if (l == 0) redm[w][r] = mm;
  }
  __syncthreads();
#pragma unroll
  for (int r = 0; r < 16; ++r) {
    float mm = redm[0][r];
#pragma unroll
    for (int q = 1; q < 8; ++q) mm = fmaxf(mm, redm[q][r]);
    e[r][0] = __expf(e[r][0] - mm);
    e[r][1] = __expf(e[r][1] - mm);
    float ss = e[r][0] + e[r][1];
#pragma unroll
    for (int off = 32; off > 0; off >>= 1) ss += __shfl_xor(ss, off);
    if (l == 0) reds[w][r] = ss;
  }
  __syncthreads();   // last lds_q read long done -> union safe as P
#pragma unroll
  for (int r = 0; r < 16; ++r) {
    float ss = reds[0][r];
#pragma unroll
    for (int q = 1; q < 8; ++q) ss += reds[q][r];
    float inv = 1.f / ss;
    int i = i0 + r;
    size_t base = ((size_t)b * NN + i) * NN + tid;
    float a0 = e[r][0] * inv, a1 = e[r][1] * inv;
    attn[base] = a0;
    attn[base + 512] = a1;
    u.P[r][tid] = f2bf(a0);
    u.P[r][tid + 512] = f2bf(a1);
  }
  __syncthreads();

  // ---- out GEMM: wave w owns c-tile w (32 channels) -----------------------
  {
    int half = l >> 5, lane31 = l & 31;
    float g = gamma[0];
    int c0 = w * 32;
    const short* vbase = vbf2 + (((size_t)(b * 128) + half) * 256 + c0 + lane31) * 8;
    const short* prow = &u.P[lane31 & 15][half * 8];
    float16v acc;
#pragma unroll
    for (int r = 0; r < 16; ++r) acc[r] = 0.f;
#pragma unroll 4
    for (int jc = 0; jc < 64; ++jc) {
      short8v av = *(const short8v*)(vbase + (size_t)jc * 2 * 256 * 8);
      short8v bv = *(const short8v*)(prow + jc * 16);
      acc = __builtin_amdgcn_mfma_f32_32x32x16_bf16(av, bv, acc, 0, 0, 0);
    }
    if (lane31 < 16) {
      int i = i0 + lane31;
#pragma unroll
      for (int r = 0; r < 16; ++r) {
        int c = c0 + (r & 3) + ((r >> 2) << 3) + (half << 2);
        size_t off = ((size_t)b * CC + c) * NN + i;
        out[off] = fmaf(g, acc[r], x[off]);
      }
    }
  }
}

extern "C" void kernel_launch(void* const* d_in, const int* in_sizes, int n_in,
                              void* d_out, int out_size, void* d_ws, size_t ws_size,
                              hipStream_t stream) {
  const float* x    = (const float*)d_in[0];
  const float* x0   = (const float*)d_in[1];
  const float* x1   = (const float*)d_in[2];
  const float* x2   = (const float*)d_in[3];
  const float* x3   = (const float*)d_in[4];
  const float* w0   = (const float*)d_in[5];
  const float* s0   = (const float*)d_in[6];
  const float* b0   = (const float*)d_in[7];
  const float* w1   = (const float*)d_in[8];
  const float* s1   = (const float*)d_in[9];
  const float* b1   = (const float*)d_in[10];
  const float* w2   = (const float*)d_in[11];
  const float* s2   = (const float*)d_in[12];
  const float* b2   = (const float*)d_in[13];
  const float* w3   = (const float*)d_in[14];
  const float* s3   = (const float*)d_in[15];
  const float* b3   = (const float*)d_in[16];
  const float* qw   = (const float*)d_in[17];
  const float* qbi  = (const float*)d_in[18];
  const float* kw   = (const float*)d_in[19];
  const float* kbi  = (const float*)d_in[20];
  const float* vw   = (const float*)d_in[21];
  const float* vbi  = (const float*)d_in[22];
  const float* relh = (const float*)d_in[23];
  const float* relw = (const float*)d_in[24];
  const float* gamma= (const float*)d_in[25];

  float* ws = (float*)d_ws;
  short* pim     = (short*)ws;                 // 2,219,520 sh
  short* multiT4 = (short*)(ws + 1109760);     // 4,194,304 sh
  float* kpbuf   = ws + 3337984;               // 131,072 f
  short* xT2     = (short*)(ws + 3469056);     // 1,048,576 sh
  short* vbf2    = (short*)(ws + 3993344);     // 1,048,576 sh
  short* wpk     = (short*)(ws + 4517632);     // 1,187,840 sh

  float* out  = (float*)d_out;
  float* attn = out + (size_t)BN * CC * NN;

  prep_kernel<<<PREP_TOT, 256, 0, stream>>>(x0, x1, x2, x3, w0, w1, w2, w3,
                                            qw, kw, vw, x, pim, wpk, xT2);

  convproj2_kernel<<<CP_TOT, 512, 0, stream>>>(pim, wpk, xT2,
                                               s0, b0, s1, b1, s2, b2, s3, b3,
                                               kbi, vbi, relh, relw,
                                               multiT4, kpbuf, vbf2);

  attnout2_kernel<<<256, 512, 0, stream>>>(multiT4, wpk, qbi, kpbuf,
                                           vbf2, x, gamma, attn, out);
}